// Round 5
// baseline (155.483 us; speedup 1.0000x reference)
//
#include <hip/hip_runtime.h>

// B=65536, Q=128, S=8, U=32
// out[b,q] = b2[q] + sum_u elu(b1[q,u] + sum_s x[b,q,s]*W1[q,s,u]) * W2[q,u]
//
// R5 structure: one q per WAVE at a time (weights -> SGPRs via uniform s_load,
// scalar pipe, zero LDS/VALU cost), lane = row (64 rows per block).
// x staged per 16-q chunk in XOR-swizzled LDS; outputs transposed through a
// 17-stride LDS tile for coalesced float4 stores.
#define Q    128
#define S    8
#define U    32
#define ROWS 64
#define QCH  16            // q per LDS chunk
#define NCH  (Q / QCH)     // 8 chunks
#define OSS  17            // out-stage row stride (floats), odd -> conflict-free

__global__ __launch_bounds__(256)
__attribute__((amdgpu_waves_per_eu(4, 4)))   // VGPR budget 128; actual ~70
void divenc_kernel(const float* __restrict__ x, const float* __restrict__ W1,
                   const float* __restrict__ b1, const float* __restrict__ W2,
                   const float* __restrict__ b2, float* __restrict__ out, int B)
{
    __shared__ float4 xs4[ROWS * 32];   // 32 KB: [row][slot], slot = f4 ^ (row&31)
    __shared__ float  os[ROWS * OSS];   // 4.25 KB out-transpose tile

    const int t     = threadIdx.x;
    const int lane  = t & 63;
    const int wv    = __builtin_amdgcn_readfirstlane(t >> 6);  // wave id 0..3, SGPR
    const int rbase = blockIdx.x * ROWS;
    const int rmax  = B - 1;

#define FMA4(H, XS, WP) { const float4 w_ = *(const float4*)&(WP);                   \
        H.x = fmaf(XS, w_.x, H.x); H.y = fmaf(XS, w_.y, H.y);                        \
        H.z = fmaf(XS, w_.z, H.z); H.w = fmaf(XS, w_.w, H.w); }
#define GSTEP(SI, XC)                                                                \
        FMA4(h0, XC, W1q[SI*U+ 0]) FMA4(h1, XC, W1q[SI*U+ 4])                        \
        FMA4(h2, XC, W1q[SI*U+ 8]) FMA4(h3, XC, W1q[SI*U+12])                        \
        FMA4(h4, XC, W1q[SI*U+16]) FMA4(h5, XC, W1q[SI*U+20])                        \
        FMA4(h6, XC, W1q[SI*U+24]) FMA4(h7, XC, W1q[SI*U+28])
// elu(v) = max(v, exp(min(v,0)) - 1), branch-free, overflow-safe
#define EL1(HV, WC) { float v_ = HV; float e_ = __expf(fminf(v_, 0.f)) - 1.f;        \
                      acc = fmaf(fmaxf(v_, e_), WC, acc); }
#define EL4(H, WP) { const float4 w_ = *(const float4*)&(WP);                        \
        EL1(H.x, w_.x) EL1(H.y, w_.y) EL1(H.z, w_.z) EL1(H.w, w_.w) }

    #pragma unroll 1
    for (int ch = 0; ch < NCH; ++ch) {
        const int q0 = ch * QCH;

        // ---- stage x chunk: 64 rows x 512B, coalesced read, swizzled write ----
        #pragma unroll
        for (int k = 0; k < 8; ++k) {
            int idx = t + k * 256;            // 0..2047
            int row = idx >> 5;
            int f4  = idx & 31;
            int r   = rbase + row; if (r > rmax) r = rmax;
            float4 v = ((const float4*)(x + (size_t)r * (Q * S) + (size_t)q0 * S))[f4];
            xs4[row * 32 + (f4 ^ (row & 31))] = v;
        }
        __syncthreads();

        // ---- compute: wave wv handles q = q0 + wv*4 + qi; lane = row ----
        #pragma unroll 1
        for (int qi = 0; qi < QCH / 4; ++qi) {
            const int qr = (wv << 2) + qi;    // 0..15 (uniform per wave)
            const int q  = q0 + qr;
            const float* __restrict__ W1q = W1 + (size_t)q * (S * U);
            const float* __restrict__ b1q = b1 + (size_t)q * U;
            const float* __restrict__ w2q = W2 + (size_t)q * U;

            // x for this (row, q): 8 floats = 2 swizzled float4 LDS reads
            float4 xA = xs4[lane * 32 + ((qr * 2 + 0) ^ (lane & 31))];
            float4 xB = xs4[lane * 32 + ((qr * 2 + 1) ^ (lane & 31))];

            // h init from b1 (uniform s_loads, broadcast to lanes)
            float4 h0 = *(const float4*)&b1q[ 0], h1 = *(const float4*)&b1q[ 4],
                   h2 = *(const float4*)&b1q[ 8], h3 = *(const float4*)&b1q[12],
                   h4 = *(const float4*)&b1q[16], h5 = *(const float4*)&b1q[20],
                   h6 = *(const float4*)&b1q[24], h7 = *(const float4*)&b1q[28];

            // GEMM1: 256 v_fmac_f32 with SGPR weight operand
            GSTEP(0, xA.x) GSTEP(1, xA.y) GSTEP(2, xA.z) GSTEP(3, xA.w)
            GSTEP(4, xB.x) GSTEP(5, xB.y) GSTEP(6, xB.z) GSTEP(7, xB.w)

            // ELU + GEMM2 (w2/b2 uniform scalars)
            float acc = b2[q];
            EL4(h0, w2q[ 0]) EL4(h1, w2q[ 4]) EL4(h2, w2q[ 8]) EL4(h3, w2q[12])
            EL4(h4, w2q[16]) EL4(h5, w2q[20]) EL4(h6, w2q[24]) EL4(h7, w2q[28])

            os[lane * OSS + qr] = acc;        // conflict-free (odd stride)
        }
        __syncthreads();

        // ---- transpose-store: out[rbase..+63][q0..q0+15], coalesced float4 ----
        {
            int row = t >> 2, c = t & 3;
            float4 o;
            o.x = os[row * OSS + c * 4 + 0];
            o.y = os[row * OSS + c * 4 + 1];
            o.z = os[row * OSS + c * 4 + 2];
            o.w = os[row * OSS + c * 4 + 3];
            int r = rbase + row;
            if (r < B)
                *(float4*)(out + (size_t)r * Q + q0 + c * 4) = o;
        }
        // no third barrier needed: next chunk's os writes are after the next
        // __syncthreads(), which orders them against this chunk's os reads.
    }
#undef FMA4
#undef GSTEP
#undef EL1
#undef EL4
}

extern "C" void kernel_launch(void* const* d_in, const int* in_sizes, int n_in,
                              void* d_out, int out_size, void* d_ws, size_t ws_size,
                              hipStream_t stream) {
    const float* x  = (const float*)d_in[0];
    const float* W1 = (const float*)d_in[1];
    const float* b1 = (const float*)d_in[2];
    const float* W2 = (const float*)d_in[3];
    const float* b2 = (const float*)d_in[4];
    float* out = (float*)d_out;

    const int B = in_sizes[0] / (Q * S);
    const int nblocks = (B + ROWS - 1) / ROWS;
    hipLaunchKernelGGL(divenc_kernel, dim3(nblocks), dim3(256), 0, stream,
                       x, W1, b1, W2, b2, out, B);
}

// Round 6
// 130.452 us; speedup vs baseline: 1.1919x; 1.1919x over previous
//
#include <hip/hip_runtime.h>

// B=65536, Q=128, S=8, U=32
// out[b,q] = b2[q] + sum_u elu(b1[q,u] + sum_s x[b,q,s]*W1[q,s,u]) * W2[q,u]
//
// R6: GEMM1 on matrix cores. v_mfma_f32_32x32x16_bf16 per (q, 32-row tile):
//   A = W1^T[q]  (M=u=32, K=s=8 padded to 16)
//   B = x rows   (N=b=32), upper-half K zeroed via mask
//   C-in = b1 (pre-permuted to C-register order)
// Epilogue: ELU + GEMM2 as 16 in-lane FMAs + shfl_xor(32) half-combine.
#define Q    128
#define S    8
#define U    32
#define QCH  16            // q per x-stage chunk
#define NCH  (Q / QCH)     // 8 chunks
#define ROWS 32            // rows per block = MFMA N
#define WQ   4             // q per wave per chunk (4 waves)

typedef __attribute__((ext_vector_type(8)))  __bf16 bf16x8;
typedef __attribute__((ext_vector_type(16))) float  f32x16;

__device__ inline unsigned short f2bf(float f) {   // RTN f32->bf16
    unsigned int u = __float_as_uint(f);
    u += 0x7FFF + ((u >> 16) & 1);
    return (unsigned short)(u >> 16);
}

// ---- prep: W1T[q][u][s] bf16 ; b1F/w2F[q][half][reg] f32 in C-reg order ----
__global__ void prep_kernel(const float* __restrict__ W1, const float* __restrict__ b1,
                            const float* __restrict__ W2,
                            unsigned short* __restrict__ W1T,
                            float* __restrict__ b1F, float* __restrict__ w2F)
{
    const int q = blockIdx.x, t = threadIdx.x;     // 128 blocks x 256 threads
    const int u = t & 31, s = t >> 5;
    W1T[(q * 32 + u) * 8 + s] = f2bf(W1[(q * 8 + s) * 32 + u]);
    if (t < 32) {
        int reg = t & 15, hh = t >> 4;
        int uu  = (reg & 3) + 8 * (reg >> 2) + 4 * hh;   // verified C/D row map
        b1F[(q * 2 + hh) * 16 + reg] = b1[q * 32 + uu];
        w2F[(q * 2 + hh) * 16 + reg] = W2[q * 32 + uu];
    }
}

__global__ __launch_bounds__(256)
__attribute__((amdgpu_waves_per_eu(4, 4)))   // pin budget=128 VGPR (no squeeze->no spill)
void divenc_mfma(const float* __restrict__ x,
                 const unsigned short* __restrict__ W1T,
                 const float* __restrict__ b1F,
                 const float* __restrict__ w2F,
                 const float* __restrict__ b2,
                 float* __restrict__ out, int B)
{
    __shared__ unsigned short xs[QCH * ROWS * 8];   // 8 KB bf16, 16B-XOR-swizzled

    const int t     = threadIdx.x;
    const int lane  = t & 63;
    const int wv    = __builtin_amdgcn_readfirstlane(t >> 6);
    const int rbase = blockIdx.x * ROWS;
    const int rmax  = B - 1;
    const int bl    = lane & 31;             // b-row (as B col) / u (as A row)
    const int h     = lane >> 5;
    const unsigned int zmask = (lane < 32) ? 0xFFFFFFFFu : 0u;

    #pragma unroll 1
    for (int ch = 0; ch < NCH; ++ch) {
        const int q0 = ch * QCH;
        __syncthreads();                      // protect xs reuse
        // ---- stage x chunk: 32 rows x 16 q x 8 s, f32->bf16, swizzled ----
        #pragma unroll
        for (int k = 0; k < 4; ++k) {
            int idx = t + k * 256;            // 0..1023 float4s
            int row = idx >> 5, f4 = idx & 31;
            int r = rbase + row; if (r > rmax) r = rmax;
            float4 v = *(const float4*)(x + (size_t)r * (Q * S) + q0 * S + f4 * 4);
            int qr = f4 >> 1, sh = f4 & 1;
            // byte addr: qr*512 + (row*16 ^ ((qr&7)<<4)) + sh*8
            // write banks 2-way (free); read swizzle term wave-uniform -> conflict-free
            int ub = qr * 512 + ((row * 16) ^ ((qr & 7) << 4)) + sh * 8;
            ushort4 bv;
            bv.x = f2bf(v.x); bv.y = f2bf(v.y); bv.z = f2bf(v.z); bv.w = f2bf(v.w);
            *(ushort4*)((char*)xs + ub) = bv;
        }
        __syncthreads();

        // ---- compute: wave wv handles q = q0 + wv*4 + qi ----
        #pragma unroll 2
        for (int qi = 0; qi < WQ; ++qi) {
            const int qr = wv * WQ + qi;      // uniform per wave
            const int q  = q0 + qr;

            // B-frag: x[row=bl][s] ; lanes>=32 are k=8..15 -> zero
            uint4 bx = *(const uint4*)((const char*)xs
                         + qr * 512 + ((bl * 16) ^ ((qr & 7) << 4)));
            bx.x &= zmask; bx.y &= zmask; bx.z &= zmask; bx.w &= zmask;

            // A-frag: W1T[q][u=bl][s0..7] (upper lanes duplicate low; B=0 kills it)
            uint4 ax = *(const uint4*)(W1T + ((size_t)q * 32 + bl) * 8);

            // C-in = b1 in register order (64B aligned)
            f32x16 cin = *(const f32x16*)(b1F + ((size_t)q * 2 + h) * 16);

            f32x16 cc = __builtin_amdgcn_mfma_f32_32x32x16_bf16(
                __builtin_bit_cast(bf16x8, ax), __builtin_bit_cast(bf16x8, bx),
                cin, 0, 0, 0);

            f32x16 wr = *(const f32x16*)(w2F + ((size_t)q * 2 + h) * 16);

            float acc = 0.f;
#define EL(I) { float v_ = cc[I]; float e_ = __expf(fminf(v_, 0.f)) - 1.f;   \
                acc = fmaf(fmaxf(v_, e_), wr[I], acc); }
            EL(0)  EL(1)  EL(2)  EL(3)  EL(4)  EL(5)  EL(6)  EL(7)
            EL(8)  EL(9)  EL(10) EL(11) EL(12) EL(13) EL(14) EL(15)
#undef EL
            acc += __shfl_xor(acc, 32);       // combine u-halves

            const int r = rbase + bl;
            if (lane < 32 && r < B)
                out[(size_t)r * Q + q] = acc + b2[q];
        }
    }
}

extern "C" void kernel_launch(void* const* d_in, const int* in_sizes, int n_in,
                              void* d_out, int out_size, void* d_ws, size_t ws_size,
                              hipStream_t stream) {
    const float* x  = (const float*)d_in[0];
    const float* W1 = (const float*)d_in[1];
    const float* b1 = (const float*)d_in[2];
    const float* W2 = (const float*)d_in[3];
    const float* b2 = (const float*)d_in[4];
    float* out = (float*)d_out;

    unsigned short* W1T = (unsigned short*)d_ws;                 // 64 KB
    float*          b1F = (float*)((char*)d_ws + 65536);         // 16 KB
    float*          w2F = (float*)((char*)d_ws + 65536 + 16384); // 16 KB

    const int B = in_sizes[0] / (Q * S);

    hipLaunchKernelGGL(prep_kernel, dim3(Q), dim3(256), 0, stream,
                       W1, b1, W2, W1T, b1F, w2F);
    hipLaunchKernelGGL(divenc_mfma, dim3((B + ROWS - 1) / ROWS), dim3(256), 0, stream,
                       x, W1T, b1F, w2F, b2, out, B);
}